// Round 1
// 260.166 us; speedup vs baseline: 1.0278x; 1.0278x over previous
//
#include <hip/hip_runtime.h>
#include <hip/hip_bf16.h>
#include <math.h>

// out = (sum_{i=1..7} M^i / D_i) / sqrt(7),  D_i = sqrt(var(i))  (reference's P_i = W_i)
// Factored:  S = W1 + W2 + W3 + (Qh * W3) * (c4/c3),
//            Qh = W1 + q2*W2 + q3*W3 + q4*W4,   W_i = c_i M^i (unit-variance scaled).
// 4 matmuls (vs 6), serial depth 4 (vs 6).
// One 256-thread block (4 waves) per matrix. Wave w owns COLUMNS [16w,16w+16).
// mm1..mm3 compute M * X  (A = M, constant, in registers; B = X, per-column frags).
// MFMA C/D layout: lane holds col = lane&15 (its own column!), rows 16t+4q+r ->
// stage-to-stage exchange is 2x ds_write_b64 + 2x ds_read_b128 per lane, intra-wave.
// mm4 = Qh * W3 (commutes): Qh staged row-major via LDS + barrier; B(W3) already in regs.
// LDS: rotation swizzle k' = (k + 8*((line>>1)&7)) & 63, stride 72 (16B aligned):
// all vector accesses <=2-way bank aliasing (free); no scalar scatter transposes.

#define LDST 72   // shorts per LDS line (144 B, 16B-aligned)

using bf16x8 = __attribute__((ext_vector_type(8))) short;
using f32x4  = __attribute__((ext_vector_type(4))) float;

__device__ __forceinline__ unsigned cvt_pk_bf16(float a, float b) {
    unsigned r;
    asm("v_cvt_pk_bf16_f32 %0, %1, %2" : "=v"(r) : "v"(a), "v"(b));
    return r;   // low16 = bf16(a), high16 = bf16(b)
}
__device__ __forceinline__ float pk_lo_f(unsigned pk) { return __uint_as_float(pk << 16); }
__device__ __forceinline__ float pk_hi_f(unsigned pk) { return __uint_as_float(pk & 0xffff0000u); }
__device__ __forceinline__ float bf2f(short s) {
    return __uint_as_float(((unsigned)(unsigned short)s) << 16);
}

// A planes: row-major [row][k], rotated by row. B planes: col-major [col][row], rotated by col.
__device__ __forceinline__ int aoff(int row, int k) {
    return row * LDST + ((k + (((row >> 1) & 7) << 3)) & 63);
}
__device__ __forceinline__ int boff(int col, int r) {
    return col * LDST + ((r + (((col >> 1) & 7) << 3)) & 63);
}

#define MM6(dst, t) do {                                                          \
    f32x4 cc = (f32x4){0.f, 0.f, 0.f, 0.f};                                       \
    cc = __builtin_amdgcn_mfma_f32_16x16x32_bf16(ah[t][0], bh[0], cc, 0, 0, 0);   \
    cc = __builtin_amdgcn_mfma_f32_16x16x32_bf16(ah[t][1], bh[1], cc, 0, 0, 0);   \
    cc = __builtin_amdgcn_mfma_f32_16x16x32_bf16(ah[t][0], bl[0], cc, 0, 0, 0);   \
    cc = __builtin_amdgcn_mfma_f32_16x16x32_bf16(ah[t][1], bl[1], cc, 0, 0, 0);   \
    cc = __builtin_amdgcn_mfma_f32_16x16x32_bf16(al[t][0], bh[0], cc, 0, 0, 0);   \
    cc = __builtin_amdgcn_mfma_f32_16x16x32_bf16(al[t][1], bh[1], cc, 0, 0, 0);   \
    dst = cc; } while (0)

__global__ __launch_bounds__(256) void power_series_kernel(
        const float* __restrict__ M, float* __restrict__ out) {
    __shared__ __align__(16) short smem[4 * 64 * LDST];   // 36864 B
    short* __restrict__ Ahi = smem;
    short* __restrict__ Alo = smem + 64 * LDST;
    short* __restrict__ Bhi = smem + 2 * 64 * LDST;
    short* __restrict__ Blo = smem + 3 * 64 * LDST;

    const int tid  = threadIdx.x;
    const int lane = tid & 63;
    const int wv   = tid >> 6;       // wave 0..3: owns columns [16wv, 16wv+16)
    const int q    = lane >> 4;      // 0..3
    const int l15  = lane & 15;
    const int c    = wv * 16 + l15;  // this lane's output column

    const float* Mg = M   + (size_t)blockIdx.x * 4096;
    float*       Og = out + (size_t)blockIdx.x * 4096;

    // ---- stage M -> A planes (row-major, hi/lo bf16 split), coalesced float4
    {
        const float4* Mg4 = reinterpret_cast<const float4*>(Mg);
        #pragma unroll
        for (int v = 0; v < 4; ++v) {
            const int idx = tid + 256 * v;
            float4 x = Mg4[idx];
            const int row = (idx * 4) >> 6;
            const int col = (idx * 4) & 63;              // multiple of 4
            unsigned h0 = cvt_pk_bf16(x.x, x.y);
            unsigned h1 = cvt_pk_bf16(x.z, x.w);
            unsigned l0 = cvt_pk_bf16(x.x - pk_lo_f(h0), x.y - pk_hi_f(h0));
            unsigned l1 = cvt_pk_bf16(x.z - pk_lo_f(h1), x.w - pk_hi_f(h1));
            *reinterpret_cast<uint2*>(&Ahi[aoff(row, col)]) = make_uint2(h0, h1);
            *reinterpret_cast<uint2*>(&Alo[aoff(row, col)]) = make_uint2(l0, l1);
        }
    }
    __syncthreads();                                     // B0

    // ---- A fragments of M (constant over mm1..mm3): lane holds M[16t+l15][32kb+8q+j]
    bf16x8 ah[4][2], al[4][2];
    #pragma unroll
    for (int t = 0; t < 4; ++t)
        #pragma unroll
        for (int kb = 0; kb < 2; ++kb) {
            const int row = 16 * t + l15;
            const int k   = 32 * kb + 8 * q;
            ah[t][kb] = *reinterpret_cast<const bf16x8*>(&Ahi[aoff(row, k)]);
            al[t][kb] = *reinterpret_cast<const bf16x8*>(&Alo[aoff(row, k)]);
        }

    // ---- gather column c of M (C-layout rows 16t+4q+r): seeds accS/Qh and the
    //      transposed B planes (2-way reads; replaces the old 32-way scatter).
    f32x4 accS[4], qac[4];
    #pragma unroll
    for (int t = 0; t < 4; ++t) {
        short h4[4], l4[4];
        #pragma unroll
        for (int r = 0; r < 4; ++r) {
            const int row = 16 * t + 4 * q + r;
            h4[r] = Ahi[aoff(row, c)];
            l4[r] = Alo[aoff(row, c)];
        }
        short4 hv; hv.x = h4[0]; hv.y = h4[1]; hv.z = h4[2]; hv.w = h4[3];
        short4 lv; lv.x = l4[0]; lv.y = l4[1]; lv.z = l4[2]; lv.w = l4[3];
        *reinterpret_cast<short4*>(&Bhi[boff(c, 16 * t + 4 * q)]) = hv;
        *reinterpret_cast<short4*>(&Blo[boff(c, 16 * t + 4 * q)]) = lv;
        f32x4 m;
        #pragma unroll
        for (int r = 0; r < 4; ++r) m[r] = bf2f(h4[r]) + bf2f(l4[r]);
        accS[t] = m;                 // W1 contribution
        qac[t]  = m;                 // Qh: q1 = 1
    }

    // ---- B fragments of M: lane holds M[32kb+8q+j][c]
    bf16x8 bh[2], bl[2];
    #pragma unroll
    for (int kb = 0; kb < 2; ++kb) {
        const int k = 32 * kb + 8 * q;
        bh[kb] = *reinterpret_cast<const bf16x8*>(&Bhi[boff(c, k)]);
        bl[kb] = *reinterpret_cast<const bf16x8*>(&Blo[boff(c, k)]);
    }

    // ---- exact scale constants (compile-time folded doubles)
    const double V1 = 64.0, V2 = 4104.0, V3 = 263696.0, V4 = 17021060.0,
                 V5 = 1104218816.0, V6 = 72260728960.0;
    const float s2f = 0.125f;                       // c2
    const float s3f = (float)sqrt(V1 / V2);         // c3/c2
    const float s4f = (float)sqrt(V2 / V3);         // c4/c3
    const float q2f = (float)sqrt(V1 * V3 / V4);    // c5/(c2*c4)
    const float q3f = (float)sqrt(V2 * V3 / V5);    // c6/(c3*c4)
    const float qs4 = (float)(sqrt(V2 / V3) * (V3 / sqrt(V6)));  // s4*q4
    const float osc = (float)(1.0 / sqrt(7.0));

    f32x4 T[4];

    // ================= mm1: W2 = (M*M) * s2 =================
    #pragma unroll
    for (int t = 0; t < 4; ++t) MM6(T[t], t);
    #pragma unroll
    for (int t = 0; t < 4; ++t) {
        float p0 = T[t][0] * s2f, p1 = T[t][1] * s2f,
              p2 = T[t][2] * s2f, p3 = T[t][3] * s2f;
        accS[t][0] += p0; accS[t][1] += p1; accS[t][2] += p2; accS[t][3] += p3;
        qac[t][0] = fmaf(q2f, p0, qac[t][0]); qac[t][1] = fmaf(q2f, p1, qac[t][1]);
        qac[t][2] = fmaf(q2f, p2, qac[t][2]); qac[t][3] = fmaf(q2f, p3, qac[t][3]);
        unsigned h0 = cvt_pk_bf16(p0, p1), h1 = cvt_pk_bf16(p2, p3);
        unsigned l0 = cvt_pk_bf16(p0 - pk_lo_f(h0), p1 - pk_hi_f(h0));
        unsigned l1 = cvt_pk_bf16(p2 - pk_lo_f(h1), p3 - pk_hi_f(h1));
        *reinterpret_cast<uint2*>(&Bhi[boff(c, 16 * t + 4 * q)]) = make_uint2(h0, h1);
        *reinterpret_cast<uint2*>(&Blo[boff(c, 16 * t + 4 * q)]) = make_uint2(l0, l1);
    }
    #pragma unroll
    for (int kb = 0; kb < 2; ++kb) {     // B frags of W2 (intra-wave, DS-ordered)
        const int k = 32 * kb + 8 * q;
        bh[kb] = *reinterpret_cast<const bf16x8*>(&Bhi[boff(c, k)]);
        bl[kb] = *reinterpret_cast<const bf16x8*>(&Blo[boff(c, k)]);
    }

    // ================= mm2: W3 = (M*W2) * s3 =================
    #pragma unroll
    for (int t = 0; t < 4; ++t) MM6(T[t], t);
    #pragma unroll
    for (int t = 0; t < 4; ++t) {
        float p0 = T[t][0] * s3f, p1 = T[t][1] * s3f,
              p2 = T[t][2] * s3f, p3 = T[t][3] * s3f;
        accS[t][0] += p0; accS[t][1] += p1; accS[t][2] += p2; accS[t][3] += p3;
        qac[t][0] = fmaf(q3f, p0, qac[t][0]); qac[t][1] = fmaf(q3f, p1, qac[t][1]);
        qac[t][2] = fmaf(q3f, p2, qac[t][2]); qac[t][3] = fmaf(q3f, p3, qac[t][3]);
        unsigned h0 = cvt_pk_bf16(p0, p1), h1 = cvt_pk_bf16(p2, p3);
        unsigned l0 = cvt_pk_bf16(p0 - pk_lo_f(h0), p1 - pk_hi_f(h0));
        unsigned l1 = cvt_pk_bf16(p2 - pk_lo_f(h1), p3 - pk_hi_f(h1));
        *reinterpret_cast<uint2*>(&Bhi[boff(c, 16 * t + 4 * q)]) = make_uint2(h0, h1);
        *reinterpret_cast<uint2*>(&Blo[boff(c, 16 * t + 4 * q)]) = make_uint2(l0, l1);
    }
    #pragma unroll
    for (int kb = 0; kb < 2; ++kb) {     // B frags of W3 (kept live through mm4!)
        const int k = 32 * kb + 8 * q;
        bh[kb] = *reinterpret_cast<const bf16x8*>(&Bhi[boff(c, k)]);
        bl[kb] = *reinterpret_cast<const bf16x8*>(&Blo[boff(c, k)]);
    }

    // ================= mm3: W4 contribution -> Qh only =================
    #pragma unroll
    for (int t = 0; t < 4; ++t) MM6(T[t], t);
    #pragma unroll
    for (int t = 0; t < 4; ++t) {
        #pragma unroll
        for (int r = 0; r < 4; ++r)
            qac[t][r] = fmaf(qs4, T[t][r], qac[t][r]);   // q4 * (T*s4)
    }

    // ---- stage Qh row-major into A planes (needs full matrix as mm4's A operand)
    __syncthreads();                                     // B1: A-plane reads done everywhere
    #pragma unroll
    for (int t = 0; t < 4; ++t) {
        unsigned h0 = cvt_pk_bf16(qac[t][0], qac[t][1]);
        unsigned h1 = cvt_pk_bf16(qac[t][2], qac[t][3]);
        unsigned l0 = cvt_pk_bf16(qac[t][0] - pk_lo_f(h0), qac[t][1] - pk_hi_f(h0));
        unsigned l1 = cvt_pk_bf16(qac[t][2] - pk_lo_f(h1), qac[t][3] - pk_hi_f(h1));
        const int r0 = 16 * t + 4 * q;
        Ahi[aoff(r0 + 0, c)] = (short)(h0 & 0xffffu);
        Ahi[aoff(r0 + 1, c)] = (short)(h0 >> 16);
        Ahi[aoff(r0 + 2, c)] = (short)(h1 & 0xffffu);
        Ahi[aoff(r0 + 3, c)] = (short)(h1 >> 16);
        Alo[aoff(r0 + 0, c)] = (short)(l0 & 0xffffu);
        Alo[aoff(r0 + 1, c)] = (short)(l0 >> 16);
        Alo[aoff(r0 + 2, c)] = (short)(l1 & 0xffffu);
        Alo[aoff(r0 + 3, c)] = (short)(l1 >> 16);
    }
    __syncthreads();                                     // B2: Qh visible to all

    // ---- A fragments of Qh (reuse registers)
    #pragma unroll
    for (int t = 0; t < 4; ++t)
        #pragma unroll
        for (int kb = 0; kb < 2; ++kb) {
            const int row = 16 * t + l15;
            const int k   = 32 * kb + 8 * q;
            ah[t][kb] = *reinterpret_cast<const bf16x8*>(&Ahi[aoff(row, k)]);
            al[t][kb] = *reinterpret_cast<const bf16x8*>(&Alo[aoff(row, k)]);
        }

    // ================= mm4: tail = (Qh * W3) * s4 =================
    #pragma unroll
    for (int t = 0; t < 4; ++t) MM6(T[t], t);
    #pragma unroll
    for (int t = 0; t < 4; ++t) {
        #pragma unroll
        for (int r = 0; r < 4; ++r)
            accS[t][r] = fmaf(s4f, T[t][r], accS[t][r]);
    }

    // ---- epilogue: transpose through LDS overlay, coalesced float4 stores
    __syncthreads();                                     // B3: all LDS reads done
    float* EP = reinterpret_cast<float*>(smem);          // [64][68] f32 overlay (17408 B)
    #pragma unroll
    for (int t = 0; t < 4; ++t) {
        #pragma unroll
        for (int r = 0; r < 4; ++r)
            EP[(16 * t + 4 * q + r) * 68 + c] = accS[t][r] * osc;
    }
    __syncthreads();                                     // B4
    {
        const int row = tid >> 2;
        const int cb  = (tid & 3) * 16;
        #pragma unroll
        for (int u = 0; u < 4; ++u) {
            float4 vv = *reinterpret_cast<const float4*>(&EP[row * 68 + cb + 4 * u]);
            *reinterpret_cast<float4*>(&Og[row * 64 + cb + 4 * u]) = vv;
        }
    }
}

extern "C" void kernel_launch(void* const* d_in, const int* in_sizes, int n_in,
                              void* d_out, int out_size, void* d_ws, size_t ws_size,
                              hipStream_t stream) {
    const float* M = (const float*)d_in[0];
    float* out = (float*)d_out;
    const int nmat = in_sizes[0] / 4096;   // 8192
    power_series_kernel<<<dim3(nmat), dim3(256), 0, stream>>>(M, out);
}

// Round 2
// 237.694 us; speedup vs baseline: 1.1250x; 1.0945x over previous
//
#include <hip/hip_runtime.h>
#include <hip/hip_bf16.h>
#include <math.h>

// out = (sum_{i=1..7} P_i)/sqrt(7), P_i = M^i * sqrt(var1/var_i)  (reference form).
// Paterson-Stockmeyer: S = W1+W2+W3 + s4*(W3*Qh),  Qh = W1 + q2 W2 + q3 W3 + qs4*(M*W3).
// 4 waves/block, wave owns cols [16wv,16wv+16).  A=M resident (hi) + JIT lo from LDS.
// mm0 = M*I (one-hot B in regs) yields M columns in C layout: seeds + first B-frags --
// no scalar LDS gather.  Stage-to-stage B-frag exchange: per-wave col-major strips,
// intra-wave DS order, no barrier.  mm3/mm4 accumulate MFMA directly into qac/accS via
// pre-scaled B-frags (no T).  W3 (not Qh) is restaged row-major (commute) overlapping
// mm3.  3 barriers total.  Direct f32 stores (no epilogue LDS transpose).
// __launch_bounds__(256,4): cap unified VGPR+AGPR at 128 -> 4 blocks/CU (LDS allows 4).

#define LDST 72   // shorts per LDS line (144 B, 16B-aligned)
#define MFMA __builtin_amdgcn_mfma_f32_16x16x32_bf16

using bf16x8 = __attribute__((ext_vector_type(8))) short;
using f32x4  = __attribute__((ext_vector_type(4))) float;

static __device__ __forceinline__ unsigned cvt_pk(float a, float b) {
    unsigned r; asm("v_cvt_pk_bf16_f32 %0, %1, %2" : "=v"(r) : "v"(a), "v"(b)); return r;
}
static __device__ __forceinline__ float pk_lo_f(unsigned pk){ return __uint_as_float(pk << 16); }
static __device__ __forceinline__ float pk_hi_f(unsigned pk){ return __uint_as_float(pk & 0xffff0000u); }
static __device__ __forceinline__ void split2(float p0, float p1, unsigned& h, unsigned& l) {
    h = cvt_pk(p0, p1);
    l = cvt_pk(p0 - pk_lo_f(h), p1 - pk_hi_f(h));
}
static __device__ __forceinline__ bf16x8 mk8(unsigned a, unsigned b, unsigned cc, unsigned d) {
    union { unsigned u[4]; bf16x8 v; } x; x.u[0]=a; x.u[1]=b; x.u[2]=cc; x.u[3]=d; return x.v;
}

// rotation swizzle: row-major [row][k] and col-major [col][r]; all vector ops <=2-way banks
static __device__ __forceinline__ int aoff(int row, int k) {
    return row * LDST + ((k + (((row >> 1) & 7) << 3)) & 63);
}
static __device__ __forceinline__ int boff(int col, int r) {
    return col * LDST + ((r + (((col >> 1) & 7) << 3)) & 63);
}

__global__ __launch_bounds__(256, 4) void power_series_kernel(
        const float* __restrict__ M, float* __restrict__ out) {
    __shared__ __align__(16) short smem[4 * 64 * LDST];   // 36864 B
    short* __restrict__ Ahi = smem;            // M row-major hi   (M lives here to the end)
    short* __restrict__ Alo = smem + 4608;     // M row-major lo
    short* __restrict__ Shi = smem + 9216;     // exchange strips, later W3 row-major hi
    short* __restrict__ Slo = smem + 13824;    // exchange strips, later W3 row-major lo

    const int tid  = threadIdx.x;
    const int lane = tid & 63;
    const int wv   = tid >> 6;
    const int q    = lane >> 4;
    const int l15  = lane & 15;
    const int c    = wv * 16 + l15;            // this lane's output column

    const float* Mg = M   + (size_t)blockIdx.x * 4096;
    float*       Og = out + (size_t)blockIdx.x * 4096;

    // ---- stage M -> A planes (hi/lo split), coalesced float4
    {
        const float4* Mg4 = reinterpret_cast<const float4*>(Mg);
        #pragma unroll
        for (int v = 0; v < 4; ++v) {
            const int idx = tid + 256 * v;
            float4 x = Mg4[idx];
            const int row = (idx * 4) >> 6;
            const int col = (idx * 4) & 63;
            unsigned h0, h1, l0, l1;
            split2(x.x, x.y, h0, l0);
            split2(x.z, x.w, h1, l1);
            *reinterpret_cast<uint2*>(&Ahi[aoff(row, col)]) = make_uint2(h0, h1);
            *reinterpret_cast<uint2*>(&Alo[aoff(row, col)]) = make_uint2(l0, l1);
        }
    }
    __syncthreads();                                   // B0

    // ---- resident hi A-frags of M: lane holds M[16t+l15][32kb+8q+j]
    bf16x8 ah[4][2];
    #pragma unroll
    for (int t = 0; t < 4; ++t)
        #pragma unroll
        for (int kb = 0; kb < 2; ++kb)
            ah[t][kb] = *reinterpret_cast<const bf16x8*>(&Ahi[aoff(16*t + l15, 32*kb + 8*q)]);

    // ---- one-hot identity B-frags (I[k][c]): built in registers, zero LDS traffic
    bf16x8 bi[2];
    #pragma unroll
    for (int kb = 0; kb < 2; ++kb) {
        const int d = c - 32*kb - 8*q;                 // one-hot position j in [0,8) if owner
        unsigned w[4];
        #pragma unroll
        for (int i = 0; i < 4; ++i)
            w[i] = ((d >> 1) == i) ? (0x3F80u << ((d & 1) * 16)) : 0u;
        bi[kb] = mk8(w[0], w[1], w[2], w[3]);
    }

    // ---- exact scale constants (compile-time folded)
    const double V1 = 64.0, V2 = 4104.0, V3 = 263696.0, V4 = 17021060.0,
                 V5 = 1104218816.0, V6 = 72260728960.0;
    const float s2f  = 0.125f;                          // P2 = (M*M)/8
    const float s3f  = (float)sqrt(V1 / V2);
    const float q2f  = (float)sqrt(V1 * V3 / V4);
    const float q3f  = (float)sqrt(V2 * V3 / V5);
    const float qs4  = (float)(sqrt(V2 / V3) * (V3 / sqrt(V6)));  // q4*s4
    const float betaf= (float)(sqrt(V6) / V3);          // s4/qs4
    const float osc  = (float)(1.0 / sqrt(7.0));

    const f32x4 Z = {0.f, 0.f, 0.f, 0.f};
    f32x4 accS[4], qac[4];

    // ================= mm0: M*I -> column c of M in C layout =================
    #pragma unroll
    for (int t = 0; t < 4; ++t) {
        bf16x8 x0 = *reinterpret_cast<const bf16x8*>(&Alo[aoff(16*t + l15,       8*q)]);
        bf16x8 x1 = *reinterpret_cast<const bf16x8*>(&Alo[aoff(16*t + l15, 32 +  8*q)]);
        f32x4 cc = Z;
        cc = MFMA(x0, bi[0], cc, 0, 0, 0);  cc = MFMA(x1, bi[1], cc, 0, 0, 0);
        cc = MFMA(ah[t][0], bi[0], cc, 0, 0, 0);  cc = MFMA(ah[t][1], bi[1], cc, 0, 0, 0);
        accS[t] = cc;                                   // W1
        qac[t]  = cc;                                   // Qh: q1 = 1
    }

    // exchange: write this lane's column (scaled, hi/lo split) to per-wave strip,
    // read B-frags back.  Intra-wave DS order -> no barrier.
    bf16x8 bh[2], bl[2];
#define EXCH(HIp, LOp, SRC, SCALE)                                                  \
    do {                                                                            \
        _Pragma("unroll")                                                           \
        for (int t_ = 0; t_ < 4; ++t_) {                                            \
            float p0 = SRC[t_][0]*(SCALE), p1 = SRC[t_][1]*(SCALE);                 \
            float p2 = SRC[t_][2]*(SCALE), p3 = SRC[t_][3]*(SCALE);                 \
            unsigned h0,h1,l0,l1; split2(p0,p1,h0,l0); split2(p2,p3,h1,l1);         \
            *reinterpret_cast<uint2*>(&(HIp)[boff(c, 16*t_ + 4*q)]) = make_uint2(h0,h1); \
            *reinterpret_cast<uint2*>(&(LOp)[boff(c, 16*t_ + 4*q)]) = make_uint2(l0,l1); \
        }                                                                           \
        _Pragma("unroll")                                                           \
        for (int kb_ = 0; kb_ < 2; ++kb_) {                                         \
            bh[kb_] = *reinterpret_cast<const bf16x8*>(&(HIp)[boff(c, 32*kb_ + 8*q)]); \
            bl[kb_] = *reinterpret_cast<const bf16x8*>(&(LOp)[boff(c, 32*kb_ + 8*q)]); \
        }                                                                           \
    } while (0)

// 3-pass product (lo*Bhi first: JIT lo-frags minimize co-residency with ah)
#define PASS3(DST, CIN, BH, BL, LOPLANE, LOBASEK)                                   \
    {                                                                               \
        bf16x8 x0 = *reinterpret_cast<const bf16x8*>(&(LOPLANE)[aoff(16*t + l15, (LOBASEK) + 8*q)]);      \
        bf16x8 x1 = *reinterpret_cast<const bf16x8*>(&(LOPLANE)[aoff(16*t + l15, (LOBASEK) + 32 + 8*q)]); \
        f32x4 cc = CIN;                                                             \
        cc = MFMA(x0, BH[0], cc, 0, 0, 0);  cc = MFMA(x1, BH[1], cc, 0, 0, 0);      \
        cc = MFMA(ah[t][0], BH[0], cc, 0, 0, 0);  cc = MFMA(ah[t][1], BH[1], cc, 0, 0, 0); \
        cc = MFMA(ah[t][0], BL[0], cc, 0, 0, 0);  cc = MFMA(ah[t][1], BL[1], cc, 0, 0, 0); \
        DST = cc;                                                                   \
    }

    // ================= mm1: W2 = M * (s2*M) =================
    EXCH(Shi, Slo, accS, s2f);                          // E1: B-frags = s2*M
    f32x4 T[4];
    #pragma unroll
    for (int t = 0; t < 4; ++t) PASS3(T[t], Z, bh, bl, Alo, 0)
    #pragma unroll
    for (int t = 0; t < 4; ++t)
        #pragma unroll
        for (int r = 0; r < 4; ++r) {
            accS[t][r] += T[t][r];
            qac[t][r]  = fmaf(q2f, T[t][r], qac[t][r]);
        }

    // ================= mm2: W3 = M * (s3*W2) =================
    EXCH(Shi, Slo, T, s3f);                             // E2: B-frags = s3*W2
    #pragma unroll
    for (int t = 0; t < 4; ++t) PASS3(T[t], Z, bh, bl, Alo, 0)
    unsigned ph[8], pl[8];                              // qs4*W3, kept for row-major restage
    #pragma unroll
    for (int t = 0; t < 4; ++t) {
        #pragma unroll
        for (int r = 0; r < 4; ++r) {
            accS[t][r] += T[t][r];
            qac[t][r]  = fmaf(q3f, T[t][r], qac[t][r]);
        }
        float p0 = T[t][0]*qs4, p1 = T[t][1]*qs4, p2 = T[t][2]*qs4, p3 = T[t][3]*qs4;
        split2(p0, p1, ph[2*t],   pl[2*t]);
        split2(p2, p3, ph[2*t+1], pl[2*t+1]);
        *reinterpret_cast<uint2*>(&Shi[boff(c, 16*t + 4*q)]) = make_uint2(ph[2*t], ph[2*t+1]);
        *reinterpret_cast<uint2*>(&Slo[boff(c, 16*t + 4*q)]) = make_uint2(pl[2*t], pl[2*t+1]);
    }
    #pragma unroll
    for (int kb = 0; kb < 2; ++kb) {                    // E3 frags: qs4*W3
        bh[kb] = *reinterpret_cast<const bf16x8*>(&Shi[boff(c, 32*kb + 8*q)]);
        bl[kb] = *reinterpret_cast<const bf16x8*>(&Slo[boff(c, 32*kb + 8*q)]);
    }

    __syncthreads();                                    // B1: all E3 strip reads done

    // ---- restage qs4*W3 row-major into S planes (overlaps mm3; M in A planes untouched)
    #pragma unroll
    for (int m = 0; m < 8; ++m) {
        const int r0 = 16*(m >> 1) + 4*q + 2*(m & 1);
        Shi[aoff(r0,     c)] = (short)(ph[m] & 0xffffu);
        Shi[aoff(r0 + 1, c)] = (short)(ph[m] >> 16);
        Slo[aoff(r0,     c)] = (short)(pl[m] & 0xffffu);
        Slo[aoff(r0 + 1, c)] = (short)(pl[m] >> 16);
    }

    // ================= mm3: qac += M * (qs4*W3)  (direct accumulate, no T) =================
    #pragma unroll
    for (int t = 0; t < 4; ++t) PASS3(qac[t], qac[t], bh, bl, Alo, 0)

    __syncthreads();                                    // B2: W3 row-major visible; M region free

    // ================= mm4: accS += (qs4*W3) * (beta*Qh)  == s4*(W3*Qh) =================
    EXCH(Ahi, Alo, qac, betaf);                         // E4 via dead M region: B-frags = beta*Qh
    #pragma unroll
    for (int t = 0; t < 4; ++t)                         // A-frags now = qs4*W3 (hi resident)
        #pragma unroll
        for (int kb = 0; kb < 2; ++kb)
            ah[t][kb] = *reinterpret_cast<const bf16x8*>(&Shi[aoff(16*t + l15, 32*kb + 8*q)]);
    #pragma unroll
    for (int t = 0; t < 4; ++t) PASS3(accS[t], accS[t], bh, bl, Slo, 0)

    // ---- direct stores: per instr 4 x 64B segments, L2 write-combined
    #pragma unroll
    for (int t = 0; t < 4; ++t)
        #pragma unroll
        for (int r = 0; r < 4; ++r)
            Og[(16*t + 4*q + r) * 64 + c] = accS[t][r] * osc;
}

extern "C" void kernel_launch(void* const* d_in, const int* in_sizes, int n_in,
                              void* d_out, int out_size, void* d_ws, size_t ws_size,
                              hipStream_t stream) {
    const float* M = (const float*)d_in[0];
    float* out = (float*)d_out;
    const int nmat = in_sizes[0] / 4096;   // 8192
    power_series_kernel<<<dim3(nmat), dim3(256), 0, stream>>>(M, out);
}